// Round 1
// 1154.164 us; speedup vs baseline: 1.0598x; 1.0598x over previous
//
#include <hip/hip_runtime.h>
#include <hip/hip_bf16.h>

// Problem constants
#define NTOK 8192          // B*S
#define E 1024
#define NS 6               // state count
#define MBIG (NTOK * NS)   // 49152 rows for QKV / Wo GEMMs
#define NSE ((long)NTOK * E)

typedef short short8 __attribute__((ext_vector_type(8)));   // 8 bf16 in 4 VGPRs
typedef float f32x4 __attribute__((ext_vector_type(4)));
typedef unsigned short ushort4v __attribute__((ext_vector_type(4)));

#define TM 128
#define TN 128
#define BK 64

static __device__ __forceinline__ float bf2f(unsigned short u) {
    union { unsigned int i; float f; } c; c.i = ((unsigned int)u) << 16; return c.f;
}

// ---------------------------------------------------------------------------
// fused f32 -> bf16 conversion of the 5 weight matrices (1M elems each)
struct WPtrs { const float* s[5]; __hip_bfloat16* d[5]; };
__global__ __launch_bounds__(256) void cvt5_w(WPtrs p)
{
    const int seg = blockIdx.x >> 10;              // 1024 blocks per matrix
    const int i = ((blockIdx.x & 1023) * 256 + threadIdx.x) * 4;
    const float4 v = *(const float4*)(p.s[seg] + i);
    union { __hip_bfloat16 h[4]; unsigned long long u; } pk;
    pk.h[0] = (__hip_bfloat16)v.x;
    pk.h[1] = (__hip_bfloat16)v.y;
    pk.h[2] = (__hip_bfloat16)v.z;
    pk.h[3] = (__hip_bfloat16)v.w;
    *(unsigned long long*)(p.d[seg] + i) = pk.u;
}

// f32 -> bf16, generic (SF conversion)
__global__ __launch_bounds__(256) void cvt_bulk(
    const float* __restrict__ src, __hip_bfloat16* __restrict__ dst)
{
    const long i = ((long)blockIdx.x * 256 + threadIdx.x) * 4;
    const float4 v = *(const float4*)(src + i);
    union { __hip_bfloat16 h[4]; unsigned long long u; } pk;
    pk.h[0] = (__hip_bfloat16)v.x;
    pk.h[1] = (__hip_bfloat16)v.y;
    pk.h[2] = (__hip_bfloat16)v.z;
    pk.h[3] = (__hip_bfloat16)v.w;
    *(unsigned long long*)(dst + i) = pk.u;
}

// ---------------------------------------------------------------------------
// C[M x 1024] = A_bf16 @ Wb^T + bias (pure async staging, m97 style)
// grid = (8, Mtiles). XCD-chunked swizzle: the 8 n-blocks sharing one A m-tile
// land on the SAME XCD, temporally adjacent -> A-tile is L2-resident (fetched
// once per XCD instead of 8x across XCDs via round-robin).
__global__ __launch_bounds__(256) void gemm_bt(
    const __hip_bfloat16* __restrict__ A,
    const __hip_bfloat16* __restrict__ Wb,
    const float* __restrict__ bias,
    __hip_bfloat16* __restrict__ C)
{
    __shared__ __hip_bfloat16 lA[TM * BK] __attribute__((aligned(16)));
    __shared__ __hip_bfloat16 lB[TN * BK] __attribute__((aligned(16)));

    const int tid  = threadIdx.x;
    const int wave = tid >> 6;
    const int lane = tid & 63;
    const int quad = lane >> 4;
    const int mrow = lane & 15;
    const int wr = wave >> 1;
    const int wc = wave & 1;

    // XCD-chunked bijective swizzle (gridDim.x == 8, nwg % 8 == 0):
    // hw-linear lin -> tile = (lin%8)*Gy + lin/8. XCD c (= lin%8 round-robin)
    // gets tiles [c*Gy, (c+1)*Gy): complete y-groups, consecutive in time.
    const int Gy   = gridDim.y;
    const int lin  = blockIdx.y * 8 + blockIdx.x;
    const int tile = (lin & 7) * Gy + (lin >> 3);
    const int  n0 = (tile & 7) * TN;
    const long m0 = (long)(tile >> 3) * TM;

    const int srow = lane >> 3;
    const int scol = (lane & 7) * 8;

    f32x4 acc[4][4] = {};

    for (int k0 = 0; k0 < 1024; k0 += BK) {
        __syncthreads();
#pragma unroll
        for (int it = 0; it < 4; ++it) {
            const int chunk = it * 4 + wave;
            const int row   = chunk * 8 + srow;
            const __hip_bfloat16* ga = A + (m0 + row) * 1024 + k0 + scol;
            const __hip_bfloat16* gb = Wb + (long)(n0 + row) * 1024 + k0 + scol;
            __hip_bfloat16* la = lA + row * BK + scol;
            __hip_bfloat16* lb = lB + row * BK + scol;
            __builtin_amdgcn_global_load_lds((const __attribute__((address_space(1))) void*)ga,
                                             (__attribute__((address_space(3))) void*)la, 16, 0, 0);
            __builtin_amdgcn_global_load_lds((const __attribute__((address_space(1))) void*)gb,
                                             (__attribute__((address_space(3))) void*)lb, 16, 0, 0);
        }
        __syncthreads();

#pragma unroll
        for (int kk = 0; kk < BK; kk += 32) {
            short8 af[4], bfr[4];
#pragma unroll
            for (int i = 0; i < 4; ++i)
                af[i] = *(const short8*)(lA + (wr * 64 + i * 16 + mrow) * BK + kk + quad * 8);
#pragma unroll
            for (int j = 0; j < 4; ++j)
                bfr[j] = *(const short8*)(lB + (wc * 64 + j * 16 + mrow) * BK + kk + quad * 8);
#pragma unroll
            for (int i = 0; i < 4; ++i)
#pragma unroll
                for (int j = 0; j < 4; ++j)
                    acc[i][j] = __builtin_amdgcn_mfma_f32_16x16x32_bf16(af[i], bfr[j], acc[i][j], 0, 0, 0);
        }
    }

#pragma unroll
    for (int i = 0; i < 4; ++i) {
#pragma unroll
        for (int j = 0; j < 4; ++j) {
            const int col = n0 + wc * 64 + j * 16 + mrow;
            const float bv = bias[col];
#pragma unroll
            for (int r = 0; r < 4; ++r) {
                const long row = m0 + wr * 64 + i * 16 + quad * 4 + r;
                C[row * 1024 + col] = (__hip_bfloat16)(acc[i][j][r] + bv);
            }
        }
    }
}

// ---------------------------------------------------------------------------
// C = A_f32 @ Wb^T + bias; A converted f32->bf16 during LDS staging.
// Fallback path only (used when workspace can't fit a 4th bf16 region).
__global__ __launch_bounds__(256) void gemm_a32_bt(
    const float* __restrict__ A,
    const __hip_bfloat16* __restrict__ Wb,
    const float* __restrict__ bias,
    __hip_bfloat16* __restrict__ C)
{
    __shared__ __hip_bfloat16 lA[TM * BK] __attribute__((aligned(16)));
    __shared__ __hip_bfloat16 lB[TN * BK] __attribute__((aligned(16)));

    const int tid  = threadIdx.x;
    const int wave = tid >> 6;
    const int lane = tid & 63;
    const int quad = lane >> 4;
    const int mrow = lane & 15;
    const int wr = wave >> 1;
    const int wc = wave & 1;

    const int Gy   = gridDim.y;
    const int lin  = blockIdx.y * 8 + blockIdx.x;
    const int tile = (lin & 7) * Gy + (lin >> 3);
    const int  n0 = (tile & 7) * TN;
    const long m0 = (long)(tile >> 3) * TM;

    const int srow = lane >> 3;
    const int scol = (lane & 7) * 8;

    f32x4 acc[4][4] = {};

    for (int k0 = 0; k0 < 1024; k0 += BK) {
        __syncthreads();
#pragma unroll
        for (int it = 0; it < 4; ++it) {
            const int chunk = it * 4 + wave;
            const int row   = chunk * 8 + srow;
            const __hip_bfloat16* gb = Wb + (long)(n0 + row) * 1024 + k0 + scol;
            __hip_bfloat16* lb = lB + row * BK + scol;
            __builtin_amdgcn_global_load_lds((const __attribute__((address_space(1))) void*)gb,
                                             (__attribute__((address_space(3))) void*)lb, 16, 0, 0);
        }
#pragma unroll
        for (int u = 0; u < 8; ++u) {
            const int c   = u * 256 + tid;   // 0..2047, 16 float4 per row
            const int row = c >> 4;
            const int c4  = c & 15;
            const float4 av = *(const float4*)(A + (m0 + row) * 1024 + k0 + c4 * 4);
            union { __hip_bfloat16 h[4]; unsigned long long uu; } pk;
            pk.h[0] = (__hip_bfloat16)av.x;
            pk.h[1] = (__hip_bfloat16)av.y;
            pk.h[2] = (__hip_bfloat16)av.z;
            pk.h[3] = (__hip_bfloat16)av.w;
            *(unsigned long long*)(lA + row * BK + c4 * 4) = pk.uu;
        }
        __syncthreads();

#pragma unroll
        for (int kk = 0; kk < BK; kk += 32) {
            short8 af[4], bfr[4];
#pragma unroll
            for (int i = 0; i < 4; ++i)
                af[i] = *(const short8*)(lA + (wr * 64 + i * 16 + mrow) * BK + kk + quad * 8);
#pragma unroll
            for (int j = 0; j < 4; ++j)
                bfr[j] = *(const short8*)(lB + (wc * 64 + j * 16 + mrow) * BK + kk + quad * 8);
#pragma unroll
            for (int i = 0; i < 4; ++i)
#pragma unroll
                for (int j = 0; j < 4; ++j)
                    acc[i][j] = __builtin_amdgcn_mfma_f32_16x16x32_bf16(af[i], bfr[j], acc[i][j], 0, 0, 0);
        }
    }

#pragma unroll
    for (int i = 0; i < 4; ++i) {
#pragma unroll
        for (int j = 0; j < 4; ++j) {
            const int col = n0 + wc * 64 + j * 16 + mrow;
            const float bv = bias[col];
#pragma unroll
            for (int r = 0; r < 4; ++r) {
                const long row = m0 + wr * 64 + i * 16 + quad * 4 + r;
                C[row * 1024 + col] = (__hip_bfloat16)(acc[i][j][r] + bv);
            }
        }
    }
}

// ---------------------------------------------------------------------------
// 6x6 attention. 16 lanes per head (d = 4/lane), 4 heads per wave, 2 tokens/block.
// Butterfly depth 4 (xor 1,2,4,8 stays inside the 16-lane head group).
// ctx written in-place over q: each wave reads exactly the range it writes.
__global__ __launch_bounds__(256) void attn6(
    const __hip_bfloat16* qb,
    const __hip_bfloat16* __restrict__ kb,
    const __hip_bfloat16* __restrict__ vb,
    __hip_bfloat16* ctx)
{
    const int w    = blockIdx.x * 4 + (threadIdx.x >> 6);
    const int lane = threadIdx.x & 63;
    const int n  = w >> 2;          // token
    const int hg = w & 3;           // head group (4 heads)
    const int h  = hg * 4 + (lane >> 4);
    const int sub = lane & 15;      // d-chunk index: d = sub*4 .. sub*4+3
    const long base = (long)n * 1024 + h * 64 + sub * 4;

    float qf[NS][4], kf[NS][4], vf[NS][4];
#pragma unroll
    for (int s = 0; s < NS; ++s) {
        const ushort4v qs = *(const ushort4v*)(qb + s * NSE + base);
        const ushort4v ks = *(const ushort4v*)(kb + s * NSE + base);
        const ushort4v vs = *(const ushort4v*)(vb + s * NSE + base);
#pragma unroll
        for (int c = 0; c < 4; ++c) {
            qf[s][c] = bf2f(qs[c]);
            kf[s][c] = bf2f(ks[c]);
            vf[s][c] = bf2f(vs[c]);
        }
    }

    float p[NS][NS];
#pragma unroll
    for (int i = 0; i < NS; ++i)
#pragma unroll
        for (int j = 0; j < NS; ++j) {
            float t = qf[i][0] * kf[j][0];
            t = fmaf(qf[i][1], kf[j][1], t);
            t = fmaf(qf[i][2], kf[j][2], t);
            t = fmaf(qf[i][3], kf[j][3], t);
            t += __shfl_xor(t, 1, 64);
            t += __shfl_xor(t, 2, 64);
            t += __shfl_xor(t, 4, 64);
            t += __shfl_xor(t, 8, 64);
            p[i][j] = t * 0.125f;   // 1/sqrt(64)
        }

#pragma unroll
    for (int i = 0; i < NS; ++i) {
        float m = p[i][0];
#pragma unroll
        for (int j = 1; j < NS; ++j) m = fmaxf(m, p[i][j]);
        float sum = 0.f;
#pragma unroll
        for (int j = 0; j < NS; ++j) { p[i][j] = __expf(p[i][j] - m); sum += p[i][j]; }
        const float inv = 1.0f / sum;
        float a[4] = {0.f, 0.f, 0.f, 0.f};
#pragma unroll
        for (int j = 0; j < NS; ++j)
#pragma unroll
            for (int c = 0; c < 4; ++c) a[c] = fmaf(p[i][j], vf[j][c], a[c]);
        union { __hip_bfloat16 h4[4]; unsigned long long u; } pk;
#pragma unroll
        for (int c = 0; c < 4; ++c) pk.h4[c] = (__hip_bfloat16)(a[c] * inv);
        *(unsigned long long*)(ctx + i * NSE + base) = pk.u;
    }
}

// ---------------------------------------------------------------------------
// enhanced = LN1(wo_out + sf); fused[n] = sum_s softmax(fw)[s] * enhanced[s][n]
__global__ __launch_bounds__(256) void ln1_fuse(
    const __hip_bfloat16* __restrict__ wo_out,   // [6][N][E] bf16
    const float* __restrict__ sf,                // [6][N][E] f32 (input)
    const float* __restrict__ g,
    const float* __restrict__ b,
    const float* __restrict__ fw,                // [6]
    __hip_bfloat16* __restrict__ fused)          // [N][E] bf16
{
    const int n = blockIdx.x, tid = threadIdx.x;
    const int wave = tid >> 6, lane = tid & 63;

    float w[NS];
    float mx = -1e30f;
#pragma unroll
    for (int s = 0; s < NS; ++s) { w[s] = fw[s]; mx = fmaxf(mx, w[s]); }
    float sw = 0.f;
#pragma unroll
    for (int s = 0; s < NS; ++s) { w[s] = __expf(w[s] - mx); sw += w[s]; }
    const float isw = 1.0f / sw;

    float gv[4], bv[4];
#pragma unroll
    for (int c = 0; c < 4; ++c) {
        const int e = c * 256 + tid;
        gv[c] = g[e];
        bv[c] = b[e];
    }

    __shared__ float red[2][4];
    float accf[4] = {0.f, 0.f, 0.f, 0.f};

    for (int s = 0; s < NS; ++s) {
        float x[4];
        float sum = 0.f, sq = 0.f;
#pragma unroll
        for (int c = 0; c < 4; ++c) {
            const long idx = s * NSE + (long)n * 1024 + c * 256 + tid;
            x[c] = (float)wo_out[idx] + sf[idx];
            sum += x[c];
            sq  += x[c] * x[c];
        }
#pragma unroll
        for (int off = 32; off; off >>= 1) {
            sum += __shfl_xor(sum, off, 64);
            sq  += __shfl_xor(sq,  off, 64);
        }
        if (lane == 0) { red[0][wave] = sum; red[1][wave] = sq; }
        __syncthreads();
        sum = red[0][0] + red[0][1] + red[0][2] + red[0][3];
        sq  = red[1][0] + red[1][1] + red[1][2] + red[1][3];
        __syncthreads();
        const float mu   = sum * (1.0f / 1024.0f);
        const float var  = sq * (1.0f / 1024.0f) - mu * mu;
        const float rstd = rsqrtf(var + 1e-5f);
        const float ws_  = w[s] * isw;
#pragma unroll
        for (int c = 0; c < 4; ++c)
            accf[c] += ws_ * ((x[c] - mu) * rstd * gv[c] + bv[c]);
    }
#pragma unroll
    for (int c = 0; c < 4; ++c)
        fused[(long)n * 1024 + c * 256 + tid] = (__hip_bfloat16)accf[c];
}

// ---------------------------------------------------------------------------
// out = LN2(LeakyReLU(hidden)); f32 output
__global__ __launch_bounds__(256) void ln2_out(
    const __hip_bfloat16* __restrict__ hidden,   // [N][1024] bf16 (bias added)
    const float* __restrict__ g,
    const float* __restrict__ b,
    float* __restrict__ out)
{
    const int n = blockIdx.x, tid = threadIdx.x;
    const int wave = tid >> 6, lane = tid & 63;
    __shared__ float red[2][4];

    float x[4];
    float sum = 0.f, sq = 0.f;
#pragma unroll
    for (int c = 0; c < 4; ++c) {
        float t = (float)hidden[(long)n * 1024 + c * 256 + tid];
        t = t >= 0.f ? t : 0.01f * t;     // LeakyReLU(0.01)
        x[c] = t;
        sum += t;
        sq  += t * t;
    }
#pragma unroll
    for (int off = 32; off; off >>= 1) {
        sum += __shfl_xor(sum, off, 64);
        sq  += __shfl_xor(sq,  off, 64);
    }
    if (lane == 0) { red[0][wave] = sum; red[1][wave] = sq; }
    __syncthreads();
    sum = red[0][0] + red[0][1] + red[0][2] + red[0][3];
    sq  = red[1][0] + red[1][1] + red[1][2] + red[1][3];
    const float mu   = sum * (1.0f / 1024.0f);
    const float var  = sq * (1.0f / 1024.0f) - mu * mu;
    const float rstd = rsqrtf(var + 1e-5f);
#pragma unroll
    for (int c = 0; c < 4; ++c) {
        const int e = c * 256 + tid;
        out[(long)n * 1024 + e] = (x[c] - mu) * rstd * g[e] + b[e];
    }
}

// ---------------------------------------------------------------------------
extern "C" void kernel_launch(void* const* d_in, const int* in_sizes, int n_in,
                              void* d_out, int out_size, void* d_ws, size_t ws_size,
                              hipStream_t stream)
{
    const float* SF  = (const float*)d_in[0];   // (6,B,S,E), f32
    const float* Wq  = (const float*)d_in[1];
    const float* bq  = (const float*)d_in[2];
    const float* Wk  = (const float*)d_in[3];
    const float* bk  = (const float*)d_in[4];
    const float* Wv  = (const float*)d_in[5];
    const float* bv  = (const float*)d_in[6];
    const float* Wo  = (const float*)d_in[7];
    const float* bo  = (const float*)d_in[8];
    const float* g1  = (const float*)d_in[9];
    const float* b1  = (const float*)d_in[10];
    const float* fw  = (const float*)d_in[11];
    const float* Wf  = (const float*)d_in[12];
    const float* bf_ = (const float*)d_in[13];
    const float* g2  = (const float*)d_in[14];
    const float* b2  = (const float*)d_in[15];
    float* out = (float*)d_out;

    // Region plan (each region = MBIG*1024 bf16 = 100.7 MB):
    //  Path A (ws >= 4 regions + weights, 413 MB):
    //    r0: q -> ctx (in place) -> hidden
    //    r1: k -> wo_out
    //    r2: sfb -> fused (in-place overwrite, row-safe)
    //    r3: v                         <- all-bf16 V GEMM, no gemm_a32_bt
    //  Path B (fallback, 312 MB proven safe):
    //    r0: q/ctx -> hidden; r1: k -> wo_out; r2: sfb -> v (a32 GEMM) -> fused
    const size_t REG = (size_t)MBIG * 1024 * sizeof(__hip_bfloat16);
    const size_t WTS = (size_t)5 * 1024 * 1024 * sizeof(__hip_bfloat16);
    const bool big_ws = ws_size >= 4 * REG + WTS;

    __hip_bfloat16* r0  = (__hip_bfloat16*)d_ws;
    __hip_bfloat16* r1  = r0 + (long)MBIG * 1024;
    __hip_bfloat16* r2  = r1 + (long)MBIG * 1024;
    __hip_bfloat16* r3  = r2 + (long)MBIG * 1024;                       // path A only
    __hip_bfloat16* wb  = big_ws ? (r3 + (long)MBIG * 1024) : r3;       // weights tail
    __hip_bfloat16* Wqb = wb;
    __hip_bfloat16* Wkb = Wqb + 1024 * 1024;
    __hip_bfloat16* Wvb = Wkb + 1024 * 1024;
    __hip_bfloat16* Wob = Wvb + 1024 * 1024;
    __hip_bfloat16* Wfb = Wob + 1024 * 1024;

    const dim3 blk(256);
    const dim3 gBig(8, MBIG / TM);   // nwg=3072, %8==0 -> bijective XCD swizzle
    const dim3 gSm(8, NTOK / TM);    // nwg=512,  %8==0

    // weight conversions (one fused kernel)
    WPtrs wp;
    wp.s[0] = Wq; wp.s[1] = Wk; wp.s[2] = Wv; wp.s[3] = Wo; wp.s[4] = Wf;
    wp.d[0] = Wqb; wp.d[1] = Wkb; wp.d[2] = Wvb; wp.d[3] = Wob; wp.d[4] = Wfb;
    cvt5_w<<<5 * 1024, blk, 0, stream>>>(wp);

    // SF f32 -> bf16 into r2 (sfb)
    cvt_bulk<<<MBIG, blk, 0, stream>>>(SF, r2);

    // Q, K always pure-bf16 async GEMMs
    gemm_bt<<<gBig, blk, 0, stream>>>(r2, Wqb, bq, r0);        // q
    gemm_bt<<<gBig, blk, 0, stream>>>(r2, Wkb, bk, r1);        // k

    const __hip_bfloat16* vptr;
    if (big_ws) {
        gemm_bt<<<gBig, blk, 0, stream>>>(r2, Wvb, bv, r3);    // v (bf16 A)
        vptr = r3;
    } else {
        gemm_a32_bt<<<gBig, blk, 0, stream>>>(SF, Wvb, bv, r2); // v over sfb
        vptr = r2;
    }

    // attention: ctx in-place into r0
    attn6<<<NTOK, blk, 0, stream>>>(r0, r1, vptr, r0);

    // wo_out = ctx @ Wo^T + bo -> r1 (k dead)
    gemm_bt<<<gBig, blk, 0, stream>>>(r0, Wob, bo, r1);

    // LN1 + residual (f32 SF) + weighted fusion -> fused in r2
    // (path A: overwrites sfb in place; block n reads rows n before writing row n)
    ln1_fuse<<<NTOK, blk, 0, stream>>>(r1, SF, g1, b1, fw, r2);

    // hidden = fused @ Wf^T + bf -> r0 (ctx dead)
    gemm_bt<<<gSm, blk, 0, stream>>>(r2, Wfb, bf_, r0);

    // LeakyReLU + LN2 -> out (f32)
    ln2_out<<<NTOK, blk, 0, stream>>>(r0, g2, b2, out);
}

// Round 2
// 898.123 us; speedup vs baseline: 1.3619x; 1.2851x over previous
//
#include <hip/hip_runtime.h>
#include <hip/hip_bf16.h>

// Problem constants
#define NTOK 8192          // B*S
#define E 1024
#define NS 6               // state count
#define MBIG (NTOK * NS)   // 49152 rows for QKV / Wo GEMMs
#define NSE ((long)NTOK * E)

typedef short short8 __attribute__((ext_vector_type(8)));   // 8 bf16 in 4 VGPRs
typedef float f32x4 __attribute__((ext_vector_type(4)));
typedef unsigned short ushort4v __attribute__((ext_vector_type(4)));

#define TM 128
#define TN 128
#define BK 64

static __device__ __forceinline__ float bf2f(unsigned short u) {
    union { unsigned int i; float f; } c; c.i = ((unsigned int)u) << 16; return c.f;
}

// ---------------------------------------------------------------------------
// fused f32 -> bf16 conversion of the 5 weight matrices (1M elems each)
struct WPtrs { const float* s[5]; __hip_bfloat16* d[5]; };
__global__ __launch_bounds__(256) void cvt5_w(WPtrs p)
{
    const int seg = blockIdx.x >> 10;              // 1024 blocks per matrix
    const int i = ((blockIdx.x & 1023) * 256 + threadIdx.x) * 4;
    const float4 v = *(const float4*)(p.s[seg] + i);
    union { __hip_bfloat16 h[4]; unsigned long long u; } pk;
    pk.h[0] = (__hip_bfloat16)v.x;
    pk.h[1] = (__hip_bfloat16)v.y;
    pk.h[2] = (__hip_bfloat16)v.z;
    pk.h[3] = (__hip_bfloat16)v.w;
    *(unsigned long long*)(p.d[seg] + i) = pk.u;
}

// f32 -> bf16, generic (SF conversion)
__global__ __launch_bounds__(256) void cvt_bulk(
    const float* __restrict__ src, __hip_bfloat16* __restrict__ dst)
{
    const long i = ((long)blockIdx.x * 256 + threadIdx.x) * 4;
    const float4 v = *(const float4*)(src + i);
    union { __hip_bfloat16 h[4]; unsigned long long u; } pk;
    pk.h[0] = (__hip_bfloat16)v.x;
    pk.h[1] = (__hip_bfloat16)v.y;
    pk.h[2] = (__hip_bfloat16)v.z;
    pk.h[3] = (__hip_bfloat16)v.w;
    *(unsigned long long*)(dst + i) = pk.u;
}

// ===========================================================================
// 256x256-tile 8-phase GEMM (m201 template: T1 XCD swizzle + T2 LDS XOR
// swizzle + T3/T4 counted-vmcnt 8-phase pipeline + T5 setprio).
// C[M x 1024] = A_bf16[M x 1024] @ Wb^T[1024 x 1024] + bias, C bf16.
// 512 threads = 8 waves (2M x 4N); per-wave output 128x64.
// LDS: 2 K-tile buffers x (A: 2 halves 128x64 + B: 2 halves 128x64) = 128 KiB.
// Swizzle: physical LDS (row, slot16B) holds global (row, slot ^ (row&7));
// global_load_lds dest stays linear (rule #21), source is pre-swizzled.
// ===========================================================================
#define KTILES 16   // K = 1024 = 16 x 64
#define NITER  8    // 2 K-tiles per iteration

static __device__ __forceinline__ void stage_half(
    const __hip_bfloat16* gsrc,      // (row0, k0) of the 128x64 half, lda=1024
    __hip_bfloat16* ldst, int tid)
{
#pragma unroll
    for (int piece = 0; piece < 2; ++piece) {
        const int r  = piece * 64 + (tid >> 3);
        const int s  = tid & 7;
        const int ss = s ^ (r & 7);                   // pre-swizzled source slot
        const __hip_bfloat16* g = gsrc + (long)r * 1024 + ss * 8;
        __hip_bfloat16* l = ldst + r * 64 + s * 8;    // linear dest (wave-uniform+lane*16)
        __builtin_amdgcn_global_load_lds((const __attribute__((address_space(1))) void*)g,
                                         (__attribute__((address_space(3))) void*)l, 16, 0, 0);
    }
}

static __device__ __forceinline__ short8 ld_frag(
    const __hip_bfloat16* half_base, int lr, int slot)
{
    // logical (row lr, 16B-slot) -> physical slot ^ (lr&7)
    return *(const short8*)(half_base + lr * 64 + ((slot ^ (lr & 7)) << 3));
}

// stage part: 0=A-half0, 1=A-half1, 2=B-half0, 3=B-half1 of K-tile kt
#define STAGE(kt, part)                                                         \
  {                                                                             \
    const int _b  = (kt) & 1;                                                   \
    const int _ab = (part) >> 1;                                                \
    const int _hf = (part) & 1;                                                 \
    const __hip_bfloat16* _g = (_ab == 0)                                       \
        ? A  + (m0 + _hf * 128) * 1024 + (kt) * 64                              \
        : Wb + ((long)n0 + _hf * 128) * 1024 + (kt) * 64;                       \
    stage_half(_g, &lds[((_b * 2 + _ab) * 2 + _hf) * 8192], tid);               \
  }

// One phase: ds-reads (quadrant q of K-tile kt) || stage issue || wait ->
// barrier -> lgkmcnt(0) -> setprio(1) -> 16 MFMA -> setprio(0) -> barrier.
#define PHASE(kt, q, STMT_STAGE, STMT_WAIT)                                     \
  {                                                                             \
    const int _buf = (kt) & 1;                                                  \
    const __hip_bfloat16* _Ab = &lds[((_buf * 2 + 0) * 2 + wm) * 8192];         \
    const __hip_bfloat16* _Bb = &lds[((_buf * 2 + 1) * 2 + (wn >> 1)) * 8192];  \
    if ((q) == 0) {                                                             \
      _Pragma("unroll") for (int nf = 0; nf < 4; ++nf)                          \
        _Pragma("unroll") for (int k2 = 0; k2 < 2; ++k2)                        \
          bfr[nf][k2] = ld_frag(_Bb, (wn & 1) * 64 + nf * 16 + mrow,            \
                                k2 * 4 + quad);                                 \
    }                                                                           \
    _Pragma("unroll") for (int mf = 0; mf < 2; ++mf)                            \
      _Pragma("unroll") for (int k2 = 0; k2 < 2; ++k2)                          \
        afr[mf][k2] = ld_frag(_Ab, (q) * 32 + mf * 16 + mrow, k2 * 4 + quad);   \
    STMT_STAGE;                                                                 \
    STMT_WAIT;                                                                  \
    __builtin_amdgcn_s_barrier();                                               \
    asm volatile("s_waitcnt lgkmcnt(0)" ::: "memory");                          \
    __builtin_amdgcn_sched_barrier(0);                                          \
    __builtin_amdgcn_s_setprio(1);                                              \
    _Pragma("unroll") for (int mf = 0; mf < 2; ++mf)                            \
      _Pragma("unroll") for (int nf = 0; nf < 4; ++nf)                          \
        _Pragma("unroll") for (int k2 = 0; k2 < 2; ++k2)                        \
          acc[(q) * 2 + mf][nf] = __builtin_amdgcn_mfma_f32_16x16x32_bf16(      \
              afr[mf][k2], bfr[nf][k2], acc[(q) * 2 + mf][nf], 0, 0, 0);        \
    __builtin_amdgcn_s_setprio(0);                                              \
    __builtin_amdgcn_s_barrier();                                               \
  }

__global__ __launch_bounds__(512) void gemm256(
    const __hip_bfloat16* __restrict__ A,
    const __hip_bfloat16* __restrict__ Wb,
    const float* __restrict__ bias,
    __hip_bfloat16* __restrict__ C)
{
    __shared__ __hip_bfloat16 lds[2 * 2 * 2 * 8192] __attribute__((aligned(16)));

    const int tid  = threadIdx.x;
    const int lane = tid & 63;
    const int wid  = tid >> 6;
    const int quad = lane >> 4;
    const int mrow = lane & 15;
    const int wm = wid >> 2;     // 0..1
    const int wn = wid & 3;      // 0..3

    // XCD-chunked bijective swizzle (gridDim.x == 4, nwg % 8 == 0)
    const int nwg = gridDim.x * gridDim.y;
    const int cpx = nwg >> 3;
    const int lin = blockIdx.y * gridDim.x + blockIdx.x;
    const int tile = (lin & 7) * cpx + (lin >> 3);
    const int  n0 = (tile & 3) * 256;          // gridDim.x == 4 (N = 1024)
    const long m0 = (long)(tile >> 2) * 256;

    f32x4 acc[8][4] = {};
    short8 bfr[4][2];
    short8 afr[2][2];

    // Prologue: K0 fully + K1 B-halves; wait K0 landed (leaves K1B0,B1 = 4 loads)
    STAGE(0, 0); STAGE(0, 1); STAGE(0, 2); STAGE(0, 3);
    STAGE(1, 2); STAGE(1, 3);
    asm volatile("s_waitcnt vmcnt(4)" ::: "memory");
    __builtin_amdgcn_s_barrier();

    // Steady-state stage plan per iteration i (kt0=2i in buf0, kt1=2i+1 in buf1):
    //  p1: K(2i+1)A0   p2: K(2i+1)A1   p3: K(2i+2)B0   p4: K(2i+2)B1 + vmcnt(4)
    //  p5: K(2i+2)A0   p6: K(2i+2)A1   p7: K(2i+3)B0   p8: K(2i+3)B1 + vmcnt(4)
    // Each LDS slot is written >=1 barrier after its last read:
    //  buf B-halves free after phase 1/5; buf A-halves free after phase 4/8.
    // vmcnt(4) at p4 completes K(2i+1) (B from prev p7/p8 + A from p1/p2)
    // before phase 5 reads it; at p8 completes K(2i+2) before next iter p1.
#pragma unroll 1
    for (int it = 0; it < NITER; ++it) {
        const int kt0 = 2 * it;
        const int kt1 = 2 * it + 1;
        const bool more = (it < NITER - 1);

        PHASE(kt0, 0, STAGE(kt1, 0), ((void)0));
        PHASE(kt0, 1, STAGE(kt1, 1), ((void)0));
        PHASE(kt0, 2, if (more) STAGE(kt0 + 2, 2), ((void)0));
        PHASE(kt0, 3, if (more) STAGE(kt0 + 2, 3),
              if (more) { asm volatile("s_waitcnt vmcnt(4)" ::: "memory"); }
              else      { asm volatile("s_waitcnt vmcnt(0)" ::: "memory"); });
        PHASE(kt1, 0, if (more) STAGE(kt0 + 2, 0), ((void)0));
        PHASE(kt1, 1, if (more) STAGE(kt0 + 2, 1), ((void)0));
        PHASE(kt1, 2, if (more) STAGE(kt0 + 3, 2), ((void)0));
        PHASE(kt1, 3, if (more) STAGE(kt0 + 3, 3),
              if (more) { asm volatile("s_waitcnt vmcnt(4)" ::: "memory"); });
    }

    // Epilogue: C = acc + bias (bf16)
#pragma unroll
    for (int mf = 0; mf < 8; ++mf) {
#pragma unroll
        for (int nf = 0; nf < 4; ++nf) {
            const int col = n0 + wn * 64 + nf * 16 + mrow;
            const float bv = bias[col];
#pragma unroll
            for (int r = 0; r < 4; ++r) {
                const long row = m0 + wm * 128 + mf * 16 + quad * 4 + r;
                C[row * 1024 + col] = (__hip_bfloat16)(acc[mf][nf][r] + bv);
            }
        }
    }
}

// ---------------------------------------------------------------------------
// Legacy 128x128 GEMMs — kept only for the small-workspace fallback path.
__global__ __launch_bounds__(256) void gemm_bt(
    const __hip_bfloat16* __restrict__ A,
    const __hip_bfloat16* __restrict__ Wb,
    const float* __restrict__ bias,
    __hip_bfloat16* __restrict__ C)
{
    __shared__ __hip_bfloat16 lA[TM * BK] __attribute__((aligned(16)));
    __shared__ __hip_bfloat16 lB[TN * BK] __attribute__((aligned(16)));

    const int tid  = threadIdx.x;
    const int wave = tid >> 6;
    const int lane = tid & 63;
    const int quad = lane >> 4;
    const int mrow = lane & 15;
    const int wr = wave >> 1;
    const int wc = wave & 1;

    const int Gy   = gridDim.y;
    const int lin  = blockIdx.y * 8 + blockIdx.x;
    const int tile = (lin & 7) * Gy + (lin >> 3);
    const int  n0 = (tile & 7) * TN;
    const long m0 = (long)(tile >> 3) * TM;

    const int srow = lane >> 3;
    const int scol = (lane & 7) * 8;

    f32x4 acc[4][4] = {};

    for (int k0 = 0; k0 < 1024; k0 += BK) {
        __syncthreads();
#pragma unroll
        for (int it = 0; it < 4; ++it) {
            const int chunk = it * 4 + wave;
            const int row   = chunk * 8 + srow;
            const __hip_bfloat16* ga = A + (m0 + row) * 1024 + k0 + scol;
            const __hip_bfloat16* gb = Wb + (long)(n0 + row) * 1024 + k0 + scol;
            __hip_bfloat16* la = lA + row * BK + scol;
            __hip_bfloat16* lb = lB + row * BK + scol;
            __builtin_amdgcn_global_load_lds((const __attribute__((address_space(1))) void*)ga,
                                             (__attribute__((address_space(3))) void*)la, 16, 0, 0);
            __builtin_amdgcn_global_load_lds((const __attribute__((address_space(1))) void*)gb,
                                             (__attribute__((address_space(3))) void*)lb, 16, 0, 0);
        }
        __syncthreads();

#pragma unroll
        for (int kk = 0; kk < BK; kk += 32) {
            short8 af[4], bfrg[4];
#pragma unroll
            for (int i = 0; i < 4; ++i)
                af[i] = *(const short8*)(lA + (wr * 64 + i * 16 + mrow) * BK + kk + quad * 8);
#pragma unroll
            for (int j = 0; j < 4; ++j)
                bfrg[j] = *(const short8*)(lB + (wc * 64 + j * 16 + mrow) * BK + kk + quad * 8);
#pragma unroll
            for (int i = 0; i < 4; ++i)
#pragma unroll
                for (int j = 0; j < 4; ++j)
                    acc[i][j] = __builtin_amdgcn_mfma_f32_16x16x32_bf16(af[i], bfrg[j], acc[i][j], 0, 0, 0);
        }
    }

#pragma unroll
    for (int i = 0; i < 4; ++i) {
#pragma unroll
        for (int j = 0; j < 4; ++j) {
            const int col = n0 + wc * 64 + j * 16 + mrow;
            const float bv = bias[col];
#pragma unroll
            for (int r = 0; r < 4; ++r) {
                const long row = m0 + wr * 64 + i * 16 + quad * 4 + r;
                C[row * 1024 + col] = (__hip_bfloat16)(acc[i][j][r] + bv);
            }
        }
    }
}

__global__ __launch_bounds__(256) void gemm_a32_bt(
    const float* __restrict__ A,
    const __hip_bfloat16* __restrict__ Wb,
    const float* __restrict__ bias,
    __hip_bfloat16* __restrict__ C)
{
    __shared__ __hip_bfloat16 lA[TM * BK] __attribute__((aligned(16)));
    __shared__ __hip_bfloat16 lB[TN * BK] __attribute__((aligned(16)));

    const int tid  = threadIdx.x;
    const int wave = tid >> 6;
    const int lane = tid & 63;
    const int quad = lane >> 4;
    const int mrow = lane & 15;
    const int wr = wave >> 1;
    const int wc = wave & 1;

    const int Gy   = gridDim.y;
    const int lin  = blockIdx.y * 8 + blockIdx.x;
    const int tile = (lin & 7) * Gy + (lin >> 3);
    const int  n0 = (tile & 7) * TN;
    const long m0 = (long)(tile >> 3) * TM;

    const int srow = lane >> 3;
    const int scol = (lane & 7) * 8;

    f32x4 acc[4][4] = {};

    for (int k0 = 0; k0 < 1024; k0 += BK) {
        __syncthreads();
#pragma unroll
        for (int it = 0; it < 4; ++it) {
            const int chunk = it * 4 + wave;
            const int row   = chunk * 8 + srow;
            const __hip_bfloat16* gb = Wb + (long)(n0 + row) * 1024 + k0 + scol;
            __hip_bfloat16* lb = lB + row * BK + scol;
            __builtin_amdgcn_global_load_lds((const __attribute__((address_space(1))) void*)gb,
                                             (__attribute__((address_space(3))) void*)lb, 16, 0, 0);
        }
#pragma unroll
        for (int u = 0; u < 8; ++u) {
            const int c   = u * 256 + tid;
            const int row = c >> 4;
            const int c4  = c & 15;
            const float4 av = *(const float4*)(A + (m0 + row) * 1024 + k0 + c4 * 4);
            union { __hip_bfloat16 h[4]; unsigned long long uu; } pk;
            pk.h[0] = (__hip_bfloat16)av.x;
            pk.h[1] = (__hip_bfloat16)av.y;
            pk.h[2] = (__hip_bfloat16)av.z;
            pk.h[3] = (__hip_bfloat16)av.w;
            *(unsigned long long*)(lA + row * BK + c4 * 4) = pk.uu;
        }
        __syncthreads();

#pragma unroll
        for (int kk = 0; kk < BK; kk += 32) {
            short8 af[4], bfrg[4];
#pragma unroll
            for (int i = 0; i < 4; ++i)
                af[i] = *(const short8*)(lA + (wr * 64 + i * 16 + mrow) * BK + kk + quad * 8);
#pragma unroll
            for (int j = 0; j < 4; ++j)
                bfrg[j] = *(const short8*)(lB + (wc * 64 + j * 16 + mrow) * BK + kk + quad * 8);
#pragma unroll
            for (int i = 0; i < 4; ++i)
#pragma unroll
                for (int j = 0; j < 4; ++j)
                    acc[i][j] = __builtin_amdgcn_mfma_f32_16x16x32_bf16(af[i], bfrg[j], acc[i][j], 0, 0, 0);
        }
    }

#pragma unroll
    for (int i = 0; i < 4; ++i) {
#pragma unroll
        for (int j = 0; j < 4; ++j) {
            const int col = n0 + wc * 64 + j * 16 + mrow;
            const float bv = bias[col];
#pragma unroll
            for (int r = 0; r < 4; ++r) {
                const long row = m0 + wr * 64 + i * 16 + quad * 4 + r;
                C[row * 1024 + col] = (__hip_bfloat16)(acc[i][j][r] + bv);
            }
        }
    }
}

// ---------------------------------------------------------------------------
// 6x6 attention. 16 lanes per head (d = 4/lane), 4 heads per wave, 2 tokens/block.
__global__ __launch_bounds__(256) void attn6(
    const __hip_bfloat16* qb,
    const __hip_bfloat16* __restrict__ kb,
    const __hip_bfloat16* __restrict__ vb,
    __hip_bfloat16* ctx)
{
    const int w    = blockIdx.x * 4 + (threadIdx.x >> 6);
    const int lane = threadIdx.x & 63;
    const int n  = w >> 2;          // token
    const int hg = w & 3;           // head group (4 heads)
    const int h  = hg * 4 + (lane >> 4);
    const int sub = lane & 15;      // d-chunk index: d = sub*4 .. sub*4+3
    const long base = (long)n * 1024 + h * 64 + sub * 4;

    float qf[NS][4], kf[NS][4], vf[NS][4];
#pragma unroll
    for (int s = 0; s < NS; ++s) {
        const ushort4v qs = *(const ushort4v*)(qb + s * NSE + base);
        const ushort4v ks = *(const ushort4v*)(kb + s * NSE + base);
        const ushort4v vs = *(const ushort4v*)(vb + s * NSE + base);
#pragma unroll
        for (int c = 0; c < 4; ++c) {
            qf[s][c] = bf2f(qs[c]);
            kf[s][c] = bf2f(ks[c]);
            vf[s][c] = bf2f(vs[c]);
        }
    }

    float p[NS][NS];
#pragma unroll
    for (int i = 0; i < NS; ++i)
#pragma unroll
        for (int j = 0; j < NS; ++j) {
            float t = qf[i][0] * kf[j][0];
            t = fmaf(qf[i][1], kf[j][1], t);
            t = fmaf(qf[i][2], kf[j][2], t);
            t = fmaf(qf[i][3], kf[j][3], t);
            t += __shfl_xor(t, 1, 64);
            t += __shfl_xor(t, 2, 64);
            t += __shfl_xor(t, 4, 64);
            t += __shfl_xor(t, 8, 64);
            p[i][j] = t * 0.125f;   // 1/sqrt(64)
        }

#pragma unroll
    for (int i = 0; i < NS; ++i) {
        float m = p[i][0];
#pragma unroll
        for (int j = 1; j < NS; ++j) m = fmaxf(m, p[i][j]);
        float sum = 0.f;
#pragma unroll
        for (int j = 0; j < NS; ++j) { p[i][j] = __expf(p[i][j] - m); sum += p[i][j]; }
        const float inv = 1.0f / sum;
        float a[4] = {0.f, 0.f, 0.f, 0.f};
#pragma unroll
        for (int j = 0; j < NS; ++j)
#pragma unroll
            for (int c = 0; c < 4; ++c) a[c] = fmaf(p[i][j], vf[j][c], a[c]);
        union { __hip_bfloat16 h4[4]; unsigned long long u; } pk;
#pragma unroll
        for (int c = 0; c < 4; ++c) pk.h4[c] = (__hip_bfloat16)(a[c] * inv);
        *(unsigned long long*)(ctx + i * NSE + base) = pk.u;
    }
}

// ---------------------------------------------------------------------------
// enhanced = LN1(wo_out + sf); fused[n] = sum_s softmax(fw)[s] * enhanced[s][n]
__global__ __launch_bounds__(256) void ln1_fuse(
    const __hip_bfloat16* __restrict__ wo_out,   // [6][N][E] bf16
    const float* __restrict__ sf,                // [6][N][E] f32 (input)
    const float* __restrict__ g,
    const float* __restrict__ b,
    const float* __restrict__ fw,                // [6]
    __hip_bfloat16* __restrict__ fused)          // [N][E] bf16
{
    const int n = blockIdx.x, tid = threadIdx.x;
    const int wave = tid >> 6, lane = tid & 63;

    float w[NS];
    float mx = -1e30f;
#pragma unroll
    for (int s = 0; s < NS; ++s) { w[s] = fw[s]; mx = fmaxf(mx, w[s]); }
    float sw = 0.f;
#pragma unroll
    for (int s = 0; s < NS; ++s) { w[s] = __expf(w[s] - mx); sw += w[s]; }
    const float isw = 1.0f / sw;

    float gv[4], bv[4];
#pragma unroll
    for (int c = 0; c < 4; ++c) {
        const int e = c * 256 + tid;
        gv[c] = g[e];
        bv[c] = b[e];
    }

    __shared__ float red[2][4];
    float accf[4] = {0.f, 0.f, 0.f, 0.f};

    for (int s = 0; s < NS; ++s) {
        float x[4];
        float sum = 0.f, sq = 0.f;
#pragma unroll
        for (int c = 0; c < 4; ++c) {
            const long idx = s * NSE + (long)n * 1024 + c * 256 + tid;
            x[c] = (float)wo_out[idx] + sf[idx];
            sum += x[c];
            sq  += x[c] * x[c];
        }
#pragma unroll
        for (int off = 32; off; off >>= 1) {
            sum += __shfl_xor(sum, off, 64);
            sq  += __shfl_xor(sq,  off, 64);
        }
        if (lane == 0) { red[0][wave] = sum; red[1][wave] = sq; }
        __syncthreads();
        sum = red[0][0] + red[0][1] + red[0][2] + red[0][3];
        sq  = red[1][0] + red[1][1] + red[1][2] + red[1][3];
        __syncthreads();
        const float mu   = sum * (1.0f / 1024.0f);
        const float var  = sq * (1.0f / 1024.0f) - mu * mu;
        const float rstd = rsqrtf(var + 1e-5f);
        const float ws_  = w[s] * isw;
#pragma unroll
        for (int c = 0; c < 4; ++c)
            accf[c] += ws_ * ((x[c] - mu) * rstd * gv[c] + bv[c]);
    }
#pragma unroll
    for (int c = 0; c < 4; ++c)
        fused[(long)n * 1024 + c * 256 + tid] = (__hip_bfloat16)accf[c];
}

// ---------------------------------------------------------------------------
// out = LN2(LeakyReLU(hidden)); f32 output
__global__ __launch_bounds__(256) void ln2_out(
    const __hip_bfloat16* __restrict__ hidden,   // [N][1024] bf16 (bias added)
    const float* __restrict__ g,
    const float* __restrict__ b,
    float* __restrict__ out)
{
    const int n = blockIdx.x, tid = threadIdx.x;
    const int wave = tid >> 6, lane = tid & 63;
    __shared__ float red[2][4];

    float x[4];
    float sum = 0.f, sq = 0.f;
#pragma unroll
    for (int c = 0; c < 4; ++c) {
        float t = (float)hidden[(long)n * 1024 + c * 256 + tid];
        t = t >= 0.f ? t : 0.01f * t;     // LeakyReLU(0.01)
        x[c] = t;
        sum += t;
        sq  += t * t;
    }
#pragma unroll
    for (int off = 32; off; off >>= 1) {
        sum += __shfl_xor(sum, off, 64);
        sq  += __shfl_xor(sq,  off, 64);
    }
    if (lane == 0) { red[0][wave] = sum; red[1][wave] = sq; }
    __syncthreads();
    sum = red[0][0] + red[0][1] + red[0][2] + red[0][3];
    sq  = red[1][0] + red[1][1] + red[1][2] + red[1][3];
    const float mu   = sum * (1.0f / 1024.0f);
    const float var  = sq * (1.0f / 1024.0f) - mu * mu;
    const float rstd = rsqrtf(var + 1e-5f);
#pragma unroll
    for (int c = 0; c < 4; ++c) {
        const int e = c * 256 + tid;
        out[(long)n * 1024 + e] = (x[c] - mu) * rstd * g[e] + b[e];
    }
}

// ---------------------------------------------------------------------------
extern "C" void kernel_launch(void* const* d_in, const int* in_sizes, int n_in,
                              void* d_out, int out_size, void* d_ws, size_t ws_size,
                              hipStream_t stream)
{
    const float* SF  = (const float*)d_in[0];   // (6,B,S,E), f32
    const float* Wq  = (const float*)d_in[1];
    const float* bq  = (const float*)d_in[2];
    const float* Wk  = (const float*)d_in[3];
    const float* bk  = (const float*)d_in[4];
    const float* Wv  = (const float*)d_in[5];
    const float* bv  = (const float*)d_in[6];
    const float* Wo  = (const float*)d_in[7];
    const float* bo  = (const float*)d_in[8];
    const float* g1  = (const float*)d_in[9];
    const float* b1  = (const float*)d_in[10];
    const float* fw  = (const float*)d_in[11];
    const float* Wf  = (const float*)d_in[12];
    const float* bf_ = (const float*)d_in[13];
    const float* g2  = (const float*)d_in[14];
    const float* b2  = (const float*)d_in[15];
    float* out = (float*)d_out;

    const size_t REG = (size_t)MBIG * 1024 * sizeof(__hip_bfloat16);
    const size_t WTS = (size_t)5 * 1024 * 1024 * sizeof(__hip_bfloat16);
    const bool big_ws = ws_size >= 4 * REG + WTS;

    __hip_bfloat16* r0  = (__hip_bfloat16*)d_ws;
    __hip_bfloat16* r1  = r0 + (long)MBIG * 1024;
    __hip_bfloat16* r2  = r1 + (long)MBIG * 1024;
    __hip_bfloat16* r3  = r2 + (long)MBIG * 1024;                       // path A only
    __hip_bfloat16* wb  = big_ws ? (r3 + (long)MBIG * 1024) : r3;       // weights tail
    __hip_bfloat16* Wqb = wb;
    __hip_bfloat16* Wkb = Wqb + 1024 * 1024;
    __hip_bfloat16* Wvb = Wkb + 1024 * 1024;
    __hip_bfloat16* Wob = Wvb + 1024 * 1024;
    __hip_bfloat16* Wfb = Wob + 1024 * 1024;

    const dim3 blk(256);

    // weight conversions (one fused kernel)
    WPtrs wp;
    wp.s[0] = Wq; wp.s[1] = Wk; wp.s[2] = Wv; wp.s[3] = Wo; wp.s[4] = Wf;
    wp.d[0] = Wqb; wp.d[1] = Wkb; wp.d[2] = Wvb; wp.d[3] = Wob; wp.d[4] = Wfb;
    cvt5_w<<<5 * 1024, blk, 0, stream>>>(wp);

    // SF f32 -> bf16 into r2 (sfb)
    cvt_bulk<<<MBIG, blk, 0, stream>>>(SF, r2);

    if (big_ws) {
        const dim3 blk2(512);
        const dim3 gB2(4, MBIG / 256);   // 4 x 192 = 768 blocks, %8==0
        const dim3 gS2(4, NTOK / 256);   // 4 x 32  = 128 blocks, %8==0

        gemm256<<<gB2, blk2, 0, stream>>>(r2, Wqb, bq, r0);     // q
        gemm256<<<gB2, blk2, 0, stream>>>(r2, Wkb, bk, r1);     // k
        gemm256<<<gB2, blk2, 0, stream>>>(r2, Wvb, bv, r3);     // v

        attn6<<<NTOK, blk, 0, stream>>>(r0, r1, r3, r0);        // ctx in-place

        gemm256<<<gB2, blk2, 0, stream>>>(r0, Wob, bo, r1);     // wo_out

        ln1_fuse<<<NTOK, blk, 0, stream>>>(r1, SF, g1, b1, fw, r2);

        gemm256<<<gS2, blk2, 0, stream>>>(r2, Wfb, bf_, r0);    // hidden

        ln2_out<<<NTOK, blk, 0, stream>>>(r0, g2, b2, out);
    } else {
        const dim3 gBig(8, MBIG / TM);
        const dim3 gSm(8, NTOK / TM);

        gemm_bt<<<gBig, blk, 0, stream>>>(r2, Wqb, bq, r0);
        gemm_bt<<<gBig, blk, 0, stream>>>(r2, Wkb, bk, r1);
        gemm_a32_bt<<<gBig, blk, 0, stream>>>(SF, Wvb, bv, r2);
        attn6<<<NTOK, blk, 0, stream>>>(r0, r1, r2, r0);
        gemm_bt<<<gBig, blk, 0, stream>>>(r0, Wob, bo, r1);
        ln1_fuse<<<NTOK, blk, 0, stream>>>(r1, SF, g1, b1, fw, r2);
        gemm_bt<<<gSm, blk, 0, stream>>>(r2, Wfb, bf_, r0);
        ln2_out<<<NTOK, blk, 0, stream>>>(r0, g2, b2, out);
    }
}